// Round 3
// baseline (2528.522 us; speedup 1.0000x reference)
//
#include <hip/hip_runtime.h>
#include <math.h>

__device__ __forceinline__ float gelu_f(float x) {
    const float c = 0.7978845608028654f;   // sqrt(2/pi)
    float x3 = x * x * x;
    float t = tanhf(c * (x + 0.044715f * x3));
    return 0.5f * x * (1.0f + t);
}

// ---------------------------------------------------------------------------
// zero-fill kernels (graph-capture-safe)
// ---------------------------------------------------------------------------
__global__ __launch_bounds__(256) void zero_f32(float* __restrict__ p, size_t n) {
    size_t i = (size_t)blockIdx.x * 256 + threadIdx.x;
    size_t st = (size_t)gridDim.x * 256;
    for (; i < n; i += st) p[i] = 0.0f;
}
__global__ __launch_bounds__(256) void zero_i32(int* __restrict__ p, int n) {
    int i = blockIdx.x * 256 + threadIdx.x;
    if (i < n) p[i] = 0;
}

// ---------------------------------------------------------------------------
// Tiled GEMM: C[M,N] = act(A[M,K] @ W[K,N] (+bias)), optional C += (ACCUM)
// A, W f32 row-major. BM=BN=64, BK=32, 256 thr, 4x4/thread.
// Requires K % 32 == 0, N % 64 == 0.
// ---------------------------------------------------------------------------
template<bool ACCUM, bool BIAS, bool DOGELU>
__global__ __launch_bounds__(256) void gemm_kernel(
    const float* __restrict__ A, const float* __restrict__ W,
    const float* __restrict__ bias, float* __restrict__ C,
    int Mrows, int K, int Nc)
{
    __shared__ float AsT[32][68];
    __shared__ float Ws[32][64];
    const int t  = threadIdx.x;
    const int tx = t & 15, ty = t >> 4;
    const int r0 = blockIdx.y * 64, c0 = blockIdx.x * 64;
    float acc[4][4] = {};

    for (int k0 = 0; k0 < K; k0 += 32) {
        {   // stage A tile 64x32 transposed
            int row = t >> 2;
            int col = (t & 3) * 8;
            int gr  = r0 + row;
            float4 v0 = make_float4(0, 0, 0, 0), v1 = make_float4(0, 0, 0, 0);
            if (gr < Mrows) {
                const float* p = A + (size_t)gr * K + (k0 + col);
                v0 = *(const float4*)p;
                v1 = *(const float4*)(p + 4);
            }
            AsT[col + 0][row] = v0.x; AsT[col + 1][row] = v0.y;
            AsT[col + 2][row] = v0.z; AsT[col + 3][row] = v0.w;
            AsT[col + 4][row] = v1.x; AsT[col + 5][row] = v1.y;
            AsT[col + 6][row] = v1.z; AsT[col + 7][row] = v1.w;
        }
        {   // stage W tile 32x64
            int row = t >> 3;
            int col = (t & 7) * 8;
            const float* p = W + (size_t)(k0 + row) * Nc + (c0 + col);
            float4 w0 = *(const float4*)p;
            float4 w1 = *(const float4*)(p + 4);
            Ws[row][col + 0] = w0.x; Ws[row][col + 1] = w0.y;
            Ws[row][col + 2] = w0.z; Ws[row][col + 3] = w0.w;
            Ws[row][col + 4] = w1.x; Ws[row][col + 5] = w1.y;
            Ws[row][col + 6] = w1.z; Ws[row][col + 7] = w1.w;
        }
        __syncthreads();
        #pragma unroll
        for (int kk = 0; kk < 32; ++kk) {
            float4 av = *(const float4*)&AsT[kk][ty * 4];
            float4 bv = *(const float4*)&Ws[kk][tx * 4];
            float a4[4] = {av.x, av.y, av.z, av.w};
            float b4[4] = {bv.x, bv.y, bv.z, bv.w};
            #pragma unroll
            for (int i = 0; i < 4; ++i)
                #pragma unroll
                for (int j = 0; j < 4; ++j)
                    acc[i][j] += a4[i] * b4[j];
        }
        __syncthreads();
    }

    #pragma unroll
    for (int i = 0; i < 4; ++i) {
        int gr = r0 + ty * 4 + i;
        if (gr >= Mrows) continue;
        float o[4];
        #pragma unroll
        for (int j = 0; j < 4; ++j) {
            float v = acc[i][j];
            if (BIAS)   v += bias[c0 + tx * 4 + j];
            if (DOGELU) v = gelu_f(v);
            o[j] = v;
        }
        float* pc = C + (size_t)gr * Nc + c0 + tx * 4;
        if (ACCUM) {
            float4 old = *(const float4*)pc;
            o[0] += old.x; o[1] += old.y; o[2] += old.z; o[3] += old.w;
        }
        *(float4*)pc = make_float4(o[0], o[1], o[2], o[3]);
    }
}

// ---------------------------------------------------------------------------
// CSR construction
// ---------------------------------------------------------------------------
__global__ void hist_edges(const int* __restrict__ ei, int* __restrict__ deg, int E_) {
    int e = blockIdx.x * 256 + threadIdx.x;
    if (e < E_) atomicAdd(&deg[ei[E_ + e]], 1);   // dst row
}
__global__ void hist_nodes(const int* __restrict__ batch, int* __restrict__ gcnt, int n) {
    int i = blockIdx.x * 256 + threadIdx.x;
    if (i < n) atomicAdd(&gcnt[batch[i]], 1);
}

// single-block exclusive scan; out has n+1 entries (out[n]=total)
__global__ __launch_bounds__(1024) void scan_kernel(
    const int* __restrict__ cnt, int n, int* __restrict__ out, int* __restrict__ cursor)
{
    __shared__ int part[1024];
    int t = threadIdx.x;
    int chunk = (n + 1023) / 1024;
    int base = t * chunk;
    int s = 0;
    for (int k = 0; k < chunk; ++k) { int i = base + k; if (i < n) s += cnt[i]; }
    part[t] = s;
    __syncthreads();
    for (int off = 1; off < 1024; off <<= 1) {
        int u = (t >= off) ? part[t - off] : 0;
        __syncthreads();
        part[t] += u;
        __syncthreads();
    }
    int run = part[t] - s;
    for (int k = 0; k < chunk; ++k) {
        int i = base + k;
        if (i < n) {
            out[i] = run;
            if (cursor) cursor[i] = run;
            run += cnt[i];
        }
    }
    if (t == 1023) out[n] = part[1023];
}

__global__ void scatter_kernel(const int* __restrict__ ei, int* __restrict__ cursor,
                               int* __restrict__ perm, int E_) {
    int e = blockIdx.x * 256 + threadIdx.x;
    if (e < E_) {
        int p = atomicAdd(&cursor[ei[E_ + e]], 1);
        perm[p] = e;
    }
}

// ---------------------------------------------------------------------------
// Edge geometry: distance + unit vector
// ---------------------------------------------------------------------------
__global__ __launch_bounds__(256) void geom_kernel(
    const float* __restrict__ pos, const int* __restrict__ ei,
    float* __restrict__ dist, float* __restrict__ unitv, int E_)
{
    int e = blockIdx.x * 256 + threadIdx.x;
    if (e >= E_) return;
    int s = ei[e], dn = ei[E_ + e];
    float dx = pos[s * 3 + 0] - pos[dn * 3 + 0];
    float dy = pos[s * 3 + 1] - pos[dn * 3 + 1];
    float dz = pos[s * 3 + 2] - pos[dn * 3 + 2];
    float d = sqrtf(dx * dx + dy * dy + dz * dz + 1e-12f);
    float invd = 1.0f / d;
    dist[e] = d;
    unitv[(size_t)e * 3 + 0] = dx * invd;
    unitv[(size_t)e * 3 + 1] = dy * invd;
    unitv[(size_t)e * 3 + 2] = dz * invd;
}

// ---------------------------------------------------------------------------
// h init: concat(emb[z], pos) @ W_in + b_in
// ---------------------------------------------------------------------------
__global__ __launch_bounds__(256) void init_h_kernel(
    const int* __restrict__ z, const float* __restrict__ pos,
    const float* __restrict__ emb, const float* __restrict__ W_in,
    const float* __restrict__ b_in, float* __restrict__ h)
{
    int i = blockIdx.x, d = threadIdx.x;
    float acc = b_in[d];
    int zi = z[i];
    #pragma unroll 8
    for (int k = 0; k < 32; ++k)
        acc += emb[zi * 32 + k] * W_in[k * 256 + d];
    #pragma unroll
    for (int x = 0; x < 3; ++x)
        acc += pos[i * 3 + x] * W_in[(32 + x) * 256 + d];
    h[(size_t)i * 256 + d] = acc;
}

// ---------------------------------------------------------------------------
// Per-dst-node edge attention, online softmax. Block = dst node,
// 128 threads = message channels, head = m/32. RBF computed on the fly.
// Outputs msg[N,128] and U[N,3,128], both softmax-normalized.
// ---------------------------------------------------------------------------
__global__ __launch_bounds__(128) void edge_attn_kernel(
    const int* __restrict__ rowptr, const int* __restrict__ perm,
    const int* __restrict__ ei,
    const float* __restrict__ Q, const float* __restrict__ Kf, const float* __restrict__ Vf,
    const float* __restrict__ dist, const float* __restrict__ unitv,
    const float* __restrict__ Wrbf_l,
    float* __restrict__ msg, float* __restrict__ U)
{
    __shared__ float wr[32 * 128];
    int m = threadIdx.x;
    #pragma unroll
    for (int r = 0; r < 32; ++r) wr[r * 128 + m] = Wrbf_l[r * 128 + m];
    __syncthreads();

    int i = blockIdx.x;
    int p0 = rowptr[i], p1 = rowptr[i + 1];
    float q = Q[(size_t)i * 128 + m];
    float Mx = -1e30f, S = 0.f, am = 0.f, a0 = 0.f, a1 = 0.f, a2 = 0.f;
    int lr = m & 31;
    const float PI = 3.14159265358979323846f;
    float freq = (float)(lr + 1) * (PI / 6.0f);

    for (int p = p0; p < p1; ++p) {
        int e = perm[p];
        int j = ei[e];                       // src node
        float kv = Kf[(size_t)j * 128 + m];
        float vv = Vf[(size_t)j * 128 + m];
        float pr = q * kv;
        #pragma unroll
        for (int off = 16; off; off >>= 1) pr += __shfl_xor(pr, off);
        float logit = pr * 0.1767766952966369f;   // 1/sqrt(32)
        // on-the-fly Bessel RBF: lane lr holds basis fn lr of this edge
        float d = dist[e];
        float invd = 1.0f / d;
        float env = (d < 6.0f) ? 0.5f * (cosf(PI * d * (1.0f / 6.0f)) + 1.0f) : 0.0f;
        float rr = sinf(d * freq) * invd * env;
        float ew = 0.f;
        #pragma unroll
        for (int r = 0; r < 32; ++r)
            ew += __shfl(rr, r) * wr[r * 128 + m];
        float vve = vv * ew;
        float ux = unitv[(size_t)e * 3 + 0];
        float uy = unitv[(size_t)e * 3 + 1];
        float uz = unitv[(size_t)e * 3 + 2];
        float nM = fmaxf(Mx, logit);
        float sc = __expf(Mx - nM);
        float w  = __expf(logit - nM);
        S = S * sc + w;
        float wv = w * vve;
        am = am * sc + wv;
        a0 = a0 * sc + wv * ux;
        a1 = a1 * sc + wv * uy;
        a2 = a2 * sc + wv * uz;
        Mx = nM;
    }
    float inv = 1.0f / (S + 1e-12f);
    msg[(size_t)i * 128 + m] = am * inv;
    U[((size_t)i * 3 + 0) * 128 + m] = a0 * inv;
    U[((size_t)i * 3 + 1) * 128 + m] = a1 * inv;
    U[((size_t)i * 3 + 2) * 128 + m] = a2 * inv;
}

// ---------------------------------------------------------------------------
// vnorm[i,d] = sqrt(sum_xyz vfeat[i,x,d]^2 + 1e-8)
// ---------------------------------------------------------------------------
__global__ __launch_bounds__(256) void vnorm_kernel(
    const float* __restrict__ vfeat, float* __restrict__ vn)
{
    int i = blockIdx.x, d = threadIdx.x;
    float v0 = vfeat[((size_t)i * 3 + 0) * 256 + d];
    float v1 = vfeat[((size_t)i * 3 + 1) * 256 + d];
    float v2 = vfeat[((size_t)i * 3 + 2) * 256 + d];
    vn[(size_t)i * 256 + d] = sqrtf(v0 * v0 + v1 * v1 + v2 * v2 + 1e-8f);
}

// ---------------------------------------------------------------------------
// h = layernorm(h + add) * gamma
// ---------------------------------------------------------------------------
__global__ __launch_bounds__(256) void ln_kernel(
    float* __restrict__ h, const float* __restrict__ add, const float* __restrict__ gamma_l)
{
    __shared__ float lds[4];
    int i = blockIdx.x, d = threadIdx.x;
    size_t idx = (size_t)i * 256 + d;
    float x = h[idx] + add[idx];
    float s = x;
    #pragma unroll
    for (int off = 32; off; off >>= 1) s += __shfl_xor(s, off);
    if ((d & 63) == 0) lds[d >> 6] = s;
    __syncthreads();
    float mu = (lds[0] + lds[1] + lds[2] + lds[3]) * (1.0f / 256.0f);
    __syncthreads();
    float xc = x - mu;
    float v = xc * xc;
    #pragma unroll
    for (int off = 32; off; off >>= 1) v += __shfl_xor(v, off);
    if ((d & 63) == 0) lds[d >> 6] = v;
    __syncthreads();
    float var = (lds[0] + lds[1] + lds[2] + lds[3]) * (1.0f / 256.0f);
    h[idx] = xc * rsqrtf(var + 1e-5f) * gamma_l[d];
}

// ---------------------------------------------------------------------------
// Graph pooling: softmax(h @ w_att) weighted sum per graph (batch sorted)
// ---------------------------------------------------------------------------
__global__ __launch_bounds__(256) void pool_kernel(
    const float* __restrict__ h, const float* __restrict__ w_att,
    const int* __restrict__ gptr, float* __restrict__ pooled)
{
    __shared__ float lds[4];
    int g = blockIdx.x, d = threadIdx.x;
    float wa = w_att[d];
    int n0 = gptr[g], n1 = gptr[g + 1];
    float M = -1e30f, S = 0.f, acc = 0.f;
    for (int i = n0; i < n1; ++i) {
        float hv = h[(size_t)i * 256 + d];
        float p = hv * wa;
        #pragma unroll
        for (int off = 32; off; off >>= 1) p += __shfl_xor(p, off);
        if ((d & 63) == 0) lds[d >> 6] = p;
        __syncthreads();
        float logit = lds[0] + lds[1] + lds[2] + lds[3];
        __syncthreads();
        float nM = fmaxf(M, logit);
        float sc = __expf(M - nM);
        float w  = __expf(logit - nM);
        S = S * sc + w;
        acc = acc * sc + w * hv;
        M = nM;
    }
    pooled[(size_t)g * 256 + d] = acc / (S + 1e-12f);
}

// ---------------------------------------------------------------------------
// out[g,c] = pooled[g,:] @ W_out[:,c] + b_out[c]   (f32 out)
// ---------------------------------------------------------------------------
__global__ __launch_bounds__(512) void out_kernel(
    const float* __restrict__ pooled, const float* __restrict__ W_out,
    const float* __restrict__ b_out, float* __restrict__ outp)
{
    __shared__ float ps[256];
    int g = blockIdx.x, c = threadIdx.x;
    if (c < 256) ps[c] = pooled[(size_t)g * 256 + c];
    __syncthreads();
    float acc = b_out[c];
    for (int k = 0; k < 256; ++k)
        acc += ps[k] * W_out[k * 512 + c];
    outp[(size_t)g * 512 + c] = acc;
}

// ---------------------------------------------------------------------------
extern "C" void kernel_launch(void* const* d_in, const int* in_sizes, int n_in,
                              void* d_out, int out_size, void* d_ws, size_t ws_size,
                              hipStream_t stream)
{
    const float* pos   = (const float*)d_in[0];
    const int*   z     = (const int*)d_in[1];
    const int*   batch = (const int*)d_in[2];
    const int*   ei    = (const int*)d_in[3];
    const float* emb   = (const float*)d_in[4];
    const float* W_in  = (const float*)d_in[5];
    const float* b_in  = (const float*)d_in[6];
    const float* Wq    = (const float*)d_in[7];
    const float* Wk    = (const float*)d_in[8];
    const float* Wv    = (const float*)d_in[9];
    const float* W_rbf = (const float*)d_in[10];
    const float* W_msg = (const float*)d_in[11];
    const float* W_vg  = (const float*)d_in[12];
    const float* W_vs  = (const float*)d_in[13];
    const float* W_nd  = (const float*)d_in[14];
    const float* b_nd  = (const float*)d_in[15];
    const float* gam   = (const float*)d_in[16];
    const float* watt  = (const float*)d_in[17];
    const float* W_out = (const float*)d_in[18];
    const float* b_out = (const float*)d_in[19];

    const int N = in_sizes[0] / 3;      // 20000
    const int E = in_sizes[3] / 2;      // 320000
    const int G = out_size / 512;       // 500

    // workspace bump allocator (256B aligned) — total ~161 MB
    char* ws = (char*)d_ws;
    size_t o = 0;
    auto alloc = [&](size_t bytes) -> char* {
        o = (o + 255) & ~(size_t)255;
        char* r = ws + o;
        o += bytes;
        return r;
    };
    float* f_dist = (float*)alloc((size_t)E * 4);
    float* f_unit = (float*)alloc((size_t)E * 3 * 4);
    float* f_h    = (float*)alloc((size_t)N * 256 * 4);
    float* f_vf   = (float*)alloc((size_t)N * 3 * 256 * 4);
    float* f_qkv  = (float*)alloc((size_t)N * 128 * 3 * 4);
    float* f_msg  = (float*)alloc((size_t)N * 128 * 4);
    float* f_U    = (float*)alloc((size_t)N * 3 * 128 * 4);
    float* f_pool = (float*)alloc((size_t)G * 256 * 4);
    int* i_deg    = (int*)alloc((size_t)N * 4);
    int* i_rowp   = (int*)alloc((size_t)(N + 1) * 4);
    int* i_cur    = (int*)alloc((size_t)(N + 1) * 4);
    int* i_perm   = (int*)alloc((size_t)E * 4);
    int* i_gcnt   = (int*)alloc((size_t)G * 4);
    int* i_gptr   = (int*)alloc((size_t)(G + 1) * 4);

    float* f_Q = f_qkv;
    float* f_K = f_qkv + (size_t)N * 128;
    float* f_V = f_qkv + (size_t)2 * N * 128;
    // aliases over dead regions:
    float* f_b1 = f_U;      // [N,256]: written after U is consumed
    float* f_b2 = f_qkv;    // [N,256]: written after Q,K are consumed

    // ---- setup ----
    zero_i32<<<(N + 255) / 256, 256, 0, stream>>>(i_deg, N);
    zero_i32<<<(G + 255) / 256, 256, 0, stream>>>(i_gcnt, G);
    zero_f32<<<2048, 256, 0, stream>>>(f_vf, (size_t)N * 3 * 256);

    hist_edges<<<(E + 255) / 256, 256, 0, stream>>>(ei, i_deg, E);
    scan_kernel<<<1, 1024, 0, stream>>>(i_deg, N, i_rowp, i_cur);
    scatter_kernel<<<(E + 255) / 256, 256, 0, stream>>>(ei, i_cur, i_perm, E);
    hist_nodes<<<(N + 255) / 256, 256, 0, stream>>>(batch, i_gcnt, N);
    scan_kernel<<<1, 1024, 0, stream>>>(i_gcnt, G, i_gptr, (int*)nullptr);
    geom_kernel<<<(E + 255) / 256, 256, 0, stream>>>(pos, ei, f_dist, f_unit, E);
    init_h_kernel<<<N, 256, 0, stream>>>(z, pos, emb, W_in, b_in, f_h);

    // ---- layers ----
    for (int l = 0; l < 4; ++l) {
        const float* Wq_l   = Wq   + (size_t)l * 256 * 128;
        const float* Wk_l   = Wk   + (size_t)l * 256 * 128;
        const float* Wv_l   = Wv   + (size_t)l * 256 * 128;
        const float* Wrbf_l = W_rbf+ (size_t)l * 32 * 128;
        const float* Wmsg_l = W_msg+ (size_t)l * 128 * 256;
        const float* Wvg_l  = W_vg + (size_t)l * 128 * 256;
        const float* Wvs_l  = W_vs + (size_t)l * 256 * 256;
        const float* Wnd_l  = W_nd + (size_t)l * 256 * 256;
        const float* bnd_l  = b_nd + (size_t)l * 256;
        const float* gam_l  = gam  + (size_t)l * 256;

        dim3 gQKV(128 / 64, (N + 63) / 64);
        gemm_kernel<false,false,false><<<gQKV, 256, 0, stream>>>(f_h, Wq_l, nullptr, f_Q, N, 256, 128);
        gemm_kernel<false,false,false><<<gQKV, 256, 0, stream>>>(f_h, Wk_l, nullptr, f_K, N, 256, 128);
        gemm_kernel<false,false,false><<<gQKV, 256, 0, stream>>>(f_h, Wv_l, nullptr, f_V, N, 256, 128);

        edge_attn_kernel<<<N, 128, 0, stream>>>(i_rowp, i_perm, ei, f_Q, f_K, f_V,
                                                f_dist, f_unit, Wrbf_l, f_msg, f_U);

        // vfeat += U @ W_vgate   ([3N,128] @ [128,256])  (consumes U)
        gemm_kernel<true,false,false><<<dim3(256 / 64, (3 * N + 63) / 64), 256, 0, stream>>>(
            f_U, Wvg_l, nullptr, f_vf, 3 * N, 128, 256);

        // b1 = gelu(msg @ W_msg)          (overwrites dead U)
        gemm_kernel<false,false,true><<<dim3(256 / 64, (N + 63) / 64), 256, 0, stream>>>(
            f_msg, Wmsg_l, nullptr, f_b1, N, 128, 256);
        // b2 = gelu(b1 @ W_node + b_node) (overwrites dead Q,K)
        gemm_kernel<false,true,true><<<dim3(256 / 64, (N + 63) / 64), 256, 0, stream>>>(
            f_b1, Wnd_l, bnd_l, f_b2, N, 256, 256);
        // b1 = vnorm(vfeat)
        vnorm_kernel<<<N, 256, 0, stream>>>(f_vf, f_b1);
        // b2 += vnorm @ W_vs
        gemm_kernel<true,false,false><<<dim3(256 / 64, (N + 63) / 64), 256, 0, stream>>>(
            f_b1, Wvs_l, nullptr, f_b2, N, 256, 256);

        ln_kernel<<<N, 256, 0, stream>>>(f_h, f_b2, gam_l);
    }

    // ---- readout ----
    pool_kernel<<<G, 256, 0, stream>>>(f_h, watt, i_gptr, f_pool);
    out_kernel<<<G, 512, 0, stream>>>(f_pool, W_out, b_out, (float*)d_out);
}

// Round 4
// 1399.232 us; speedup vs baseline: 1.8071x; 1.8071x over previous
//
#include <hip/hip_runtime.h>
#include <math.h>

typedef unsigned short u16;
typedef unsigned int   u32;
typedef __attribute__((ext_vector_type(8))) unsigned short ushort8;
typedef __attribute__((ext_vector_type(8))) short short8v;   // 8 bf16 (4 VGPRs)
typedef __attribute__((ext_vector_type(4))) float f32x4;

__device__ __forceinline__ float gelu_f(float x) {
    const float c = 0.7978845608028654f;   // sqrt(2/pi)
    float x3 = x * x * x;
    float t = tanhf(c * (x + 0.044715f * x3));
    return 0.5f * x * (1.0f + t);
}

// split f32 -> bf16 hi + bf16 lo (RNE both); hi+lo ~ 16-bit mantissa
__device__ __forceinline__ void split_bf16(float f, u16& h, u16& l) {
    u32 u = __float_as_uint(f);
    u32 r = (u + 0x7FFFu + ((u >> 16) & 1u)) >> 16;
    h = (u16)r;
    float hf = __uint_as_float(r << 16);
    float d = f - hf;
    u32 u2 = __float_as_uint(d);
    l = (u16)((u2 + 0x7FFFu + ((u2 >> 16) & 1u)) >> 16);
}

// ---------------------------------------------------------------------------
// zero-fill kernels (graph-capture-safe)
// ---------------------------------------------------------------------------
__global__ __launch_bounds__(256) void zero_f32(float* __restrict__ p, size_t n) {
    size_t i = (size_t)blockIdx.x * 256 + threadIdx.x;
    size_t st = (size_t)gridDim.x * 256;
    for (; i < n; i += st) p[i] = 0.0f;
}
__global__ __launch_bounds__(256) void zero_i32(int* __restrict__ p, int n) {
    int i = blockIdx.x * 256 + threadIdx.x;
    if (i < n) p[i] = 0;
}

// ---------------------------------------------------------------------------
// Weight pre-pass: transpose [K][N] f32 -> [N][K] split bf16 hi/lo
// ---------------------------------------------------------------------------
struct TEntry { const float* src; u16* dh; u16* dl; int K; int N; };
struct TDesc  { TEntry e[28]; };

__global__ __launch_bounds__(256) void transpose_split(TDesc desc) {
    __shared__ float tile[32][33];
    TEntry en = desc.e[blockIdx.y];
    int tk = en.K >> 5, tn = en.N >> 5;
    int bx = blockIdx.x;
    if (bx >= tk * tn) return;
    int k0 = (bx % tk) * 32, n0 = (bx / tk) * 32;
    int tx = threadIdx.x & 31, ty = threadIdx.x >> 5;   // 32 x 8
    #pragma unroll
    for (int yy = 0; yy < 32; yy += 8)
        tile[ty + yy][tx] = en.src[(size_t)(k0 + ty + yy) * en.N + (n0 + tx)];
    __syncthreads();
    #pragma unroll
    for (int yy = 0; yy < 32; yy += 8) {
        int n = n0 + ty + yy, k = k0 + tx;
        float f = tile[tx][ty + yy];
        u16 h, l;
        split_bf16(f, h, l);
        en.dh[(size_t)n * en.K + k] = h;
        en.dl[(size_t)n * en.K + k] = l;
    }
}

// ---------------------------------------------------------------------------
// MFMA GEMM: C[M,N] = act(A[M,K] @ B[K,N] (+bias)), optional += (ACCUM)
// A f32 row-major; B supplied pre-transposed + bf16-split: BH/BL are [N][K].
// Split product: C ~= Ah*Bh + Ah*Bl + Al*Bh  (f32-grade precision).
// Block tile 128x128, BK=32, 256 threads = 4 waves, 64x64 per wave.
// Requires K%32==0, N%128==0; M guarded.
// ---------------------------------------------------------------------------
template<bool ACCUM, bool BIAS, bool DOGELU>
__global__ __launch_bounds__(256) void mfma_gemm(
    const float* __restrict__ A, const u16* __restrict__ BH,
    const u16* __restrict__ BL, const float* __restrict__ bias,
    float* __restrict__ C, int Mrows, int K, int Nc)
{
    __shared__ __align__(16) u16 sAh[128][40];
    __shared__ __align__(16) u16 sAl[128][40];
    __shared__ __align__(16) u16 sBh[128][40];
    __shared__ __align__(16) u16 sBl[128][40];

    const int t = threadIdx.x;
    const int lane = t & 63, wid = t >> 6;
    const int r0 = blockIdx.y * 128, c0 = blockIdx.x * 128;
    const int wr = (wid >> 1) * 64, wc = (wid & 1) * 64;

    f32x4 acc[4][4] = {};

    const int srow = t >> 1;            // staging row 0..127
    const int skc  = (t & 1) * 16;      // staging k-offset 0/16

    for (int k0 = 0; k0 < K; k0 += 32) {
        // ---- stage A (f32 -> split bf16) ----
        {
            int gr = r0 + srow;
            float v[16];
            if (gr < Mrows) {
                const float* p = A + (size_t)gr * K + (k0 + skc);
                float4 q0 = *(const float4*)(p + 0);
                float4 q1 = *(const float4*)(p + 4);
                float4 q2 = *(const float4*)(p + 8);
                float4 q3 = *(const float4*)(p + 12);
                v[0]=q0.x; v[1]=q0.y; v[2]=q0.z; v[3]=q0.w;
                v[4]=q1.x; v[5]=q1.y; v[6]=q1.z; v[7]=q1.w;
                v[8]=q2.x; v[9]=q2.y; v[10]=q2.z; v[11]=q2.w;
                v[12]=q3.x; v[13]=q3.y; v[14]=q3.z; v[15]=q3.w;
            } else {
                #pragma unroll
                for (int j = 0; j < 16; ++j) v[j] = 0.f;
            }
            ushort8 h0, h1, l0, l1;
            #pragma unroll
            for (int j = 0; j < 8; ++j) { u16 hh, ll; split_bf16(v[j], hh, ll); h0[j]=hh; l0[j]=ll; }
            #pragma unroll
            for (int j = 0; j < 8; ++j) { u16 hh, ll; split_bf16(v[8+j], hh, ll); h1[j]=hh; l1[j]=ll; }
            *(ushort8*)&sAh[srow][skc]     = h0;
            *(ushort8*)&sAh[srow][skc + 8] = h1;
            *(ushort8*)&sAl[srow][skc]     = l0;
            *(ushort8*)&sAl[srow][skc + 8] = l1;
        }
        // ---- stage B (already split, copy) ----
        {
            int cg = c0 + srow;
            const u16* ph = BH + (size_t)cg * K + (k0 + skc);
            const u16* pl = BL + (size_t)cg * K + (k0 + skc);
            *(ushort8*)&sBh[srow][skc]     = *(const ushort8*)(ph);
            *(ushort8*)&sBh[srow][skc + 8] = *(const ushort8*)(ph + 8);
            *(ushort8*)&sBl[srow][skc]     = *(const ushort8*)(pl);
            *(ushort8*)&sBl[srow][skc + 8] = *(const ushort8*)(pl + 8);
        }
        __syncthreads();

        // ---- compute: wave tile 64x64 = 4x4 fragments of 16x16, K=32 ----
        const int arow = wr + (lane & 15);
        const int koff = (lane >> 4) * 8;
        short8v ah[4], al[4];
        #pragma unroll
        for (int fr = 0; fr < 4; ++fr) {
            ah[fr] = *(const short8v*)&sAh[arow + fr * 16][koff];
            al[fr] = *(const short8v*)&sAl[arow + fr * 16][koff];
        }
        #pragma unroll
        for (int fc = 0; fc < 4; ++fc) {
            int bcol = wc + fc * 16 + (lane & 15);
            short8v bh = *(const short8v*)&sBh[bcol][koff];
            short8v bl = *(const short8v*)&sBl[bcol][koff];
            #pragma unroll
            for (int fr = 0; fr < 4; ++fr) {
                acc[fr][fc] = __builtin_amdgcn_mfma_f32_16x16x32_bf16(ah[fr], bh, acc[fr][fc], 0, 0, 0);
                acc[fr][fc] = __builtin_amdgcn_mfma_f32_16x16x32_bf16(ah[fr], bl, acc[fr][fc], 0, 0, 0);
                acc[fr][fc] = __builtin_amdgcn_mfma_f32_16x16x32_bf16(al[fr], bh, acc[fr][fc], 0, 0, 0);
            }
        }
        __syncthreads();
    }

    // ---- epilogue: C/D layout col=lane&15, row=(lane>>4)*4+reg ----
    #pragma unroll
    for (int fr = 0; fr < 4; ++fr) {
        int rbase = r0 + wr + fr * 16 + (lane >> 4) * 4;
        #pragma unroll
        for (int fc = 0; fc < 4; ++fc) {
            int col = c0 + wc + fc * 16 + (lane & 15);
            #pragma unroll
            for (int reg = 0; reg < 4; ++reg) {
                int gr = rbase + reg;
                if (gr >= Mrows) continue;
                float v = acc[fr][fc][reg];
                if (BIAS)   v += bias[col];
                if (DOGELU) v = gelu_f(v);
                float* pc = C + (size_t)gr * Nc + col;
                if (ACCUM)  v += *pc;
                *pc = v;
            }
        }
    }
}

// ---------------------------------------------------------------------------
// CSR construction
// ---------------------------------------------------------------------------
__global__ void hist_edges(const int* __restrict__ ei, int* __restrict__ deg, int E_) {
    int e = blockIdx.x * 256 + threadIdx.x;
    if (e < E_) atomicAdd(&deg[ei[E_ + e]], 1);   // dst row
}
__global__ void hist_nodes(const int* __restrict__ batch, int* __restrict__ gcnt, int n) {
    int i = blockIdx.x * 256 + threadIdx.x;
    if (i < n) atomicAdd(&gcnt[batch[i]], 1);
}

__global__ __launch_bounds__(1024) void scan_kernel(
    const int* __restrict__ cnt, int n, int* __restrict__ out, int* __restrict__ cursor)
{
    __shared__ int part[1024];
    int t = threadIdx.x;
    int chunk = (n + 1023) / 1024;
    int base = t * chunk;
    int s = 0;
    for (int k = 0; k < chunk; ++k) { int i = base + k; if (i < n) s += cnt[i]; }
    part[t] = s;
    __syncthreads();
    for (int off = 1; off < 1024; off <<= 1) {
        int u = (t >= off) ? part[t - off] : 0;
        __syncthreads();
        part[t] += u;
        __syncthreads();
    }
    int run = part[t] - s;
    for (int k = 0; k < chunk; ++k) {
        int i = base + k;
        if (i < n) {
            out[i] = run;
            if (cursor) cursor[i] = run;
            run += cnt[i];
        }
    }
    if (t == 1023) out[n] = part[1023];
}

__global__ void scatter_kernel(const int* __restrict__ ei, int* __restrict__ cursor,
                               int* __restrict__ perm, int E_) {
    int e = blockIdx.x * 256 + threadIdx.x;
    if (e < E_) {
        int p = atomicAdd(&cursor[ei[E_ + e]], 1);
        perm[p] = e;
    }
}

// ---------------------------------------------------------------------------
// Edge geometry: distance + unit vector
// ---------------------------------------------------------------------------
__global__ __launch_bounds__(256) void geom_kernel(
    const float* __restrict__ pos, const int* __restrict__ ei,
    float* __restrict__ dist, float* __restrict__ unitv, int E_)
{
    int e = blockIdx.x * 256 + threadIdx.x;
    if (e >= E_) return;
    int s = ei[e], dn = ei[E_ + e];
    float dx = pos[s * 3 + 0] - pos[dn * 3 + 0];
    float dy = pos[s * 3 + 1] - pos[dn * 3 + 1];
    float dz = pos[s * 3 + 2] - pos[dn * 3 + 2];
    float d = sqrtf(dx * dx + dy * dy + dz * dz + 1e-12f);
    float invd = 1.0f / d;
    dist[e] = d;
    unitv[(size_t)e * 3 + 0] = dx * invd;
    unitv[(size_t)e * 3 + 1] = dy * invd;
    unitv[(size_t)e * 3 + 2] = dz * invd;
}

// ---------------------------------------------------------------------------
// h init: concat(emb[z], pos) @ W_in + b_in
// ---------------------------------------------------------------------------
__global__ __launch_bounds__(256) void init_h_kernel(
    const int* __restrict__ z, const float* __restrict__ pos,
    const float* __restrict__ emb, const float* __restrict__ W_in,
    const float* __restrict__ b_in, float* __restrict__ h)
{
    int i = blockIdx.x, d = threadIdx.x;
    float acc = b_in[d];
    int zi = z[i];
    #pragma unroll 8
    for (int k = 0; k < 32; ++k)
        acc += emb[zi * 32 + k] * W_in[k * 256 + d];
    #pragma unroll
    for (int x = 0; x < 3; ++x)
        acc += pos[i * 3 + x] * W_in[(32 + x) * 256 + d];
    h[(size_t)i * 256 + d] = acc;
}

// ---------------------------------------------------------------------------
// Per-dst-node edge attention, online softmax. Block = dst node,
// 128 threads = message channels, head = m/32.
// W_rbf column held in 32 registers; Bessel basis via sin recurrence
// (no LDS traffic in the edge loop). qkv is fused [N,384] = [q|k|v].
// ---------------------------------------------------------------------------
__global__ __launch_bounds__(128) void edge_attn_kernel(
    const int* __restrict__ rowptr, const int* __restrict__ perm,
    const int* __restrict__ ei,
    const float* __restrict__ qkv,
    const float* __restrict__ dist, const float* __restrict__ unitv,
    const float* __restrict__ Wrbf_l,
    float* __restrict__ msg, float* __restrict__ U)
{
    int m = threadIdx.x;
    int i = blockIdx.x;

    float wreg[32];
    #pragma unroll
    for (int r = 0; r < 32; ++r) wreg[r] = Wrbf_l[r * 128 + m];

    int p0 = rowptr[i], p1 = rowptr[i + 1];
    float q = qkv[(size_t)i * 384 + m];
    float Mx = -1e30f, S = 0.f, am = 0.f, a0 = 0.f, a1 = 0.f, a2 = 0.f;
    const float PI = 3.14159265358979323846f;

    for (int p = p0; p < p1; ++p) {
        int e = perm[p];
        int j = ei[e];                       // src node
        float kv = qkv[(size_t)j * 384 + 128 + m];
        float vv = qkv[(size_t)j * 384 + 256 + m];
        float pr = q * kv;
        #pragma unroll
        for (int off = 16; off; off >>= 1) pr += __shfl_xor(pr, off);
        float logit = pr * 0.1767766952966369f;   // 1/sqrt(32)

        // Bessel RBF filter: ew = sum_r sin((r+1)θ)·invd·env · wreg[r], θ=πd/6
        float d = dist[e];
        float invd = 1.0f / d;
        float th = d * (PI / 6.0f);
        float s1, c1;
        __sincosf(th, &s1, &c1);
        float env = (d < 6.0f) ? (0.5f * c1 + 0.5f) : 0.0f;
        float two_c = 2.0f * c1;
        float sp = 0.f, sc = s1, dot = 0.f;
        #pragma unroll
        for (int r = 0; r < 32; ++r) {
            dot = fmaf(sc, wreg[r], dot);
            float sn = fmaf(two_c, sc, -sp);
            sp = sc; sc = sn;
        }
        float ew = dot * invd * env;

        float vve = vv * ew;
        float ux = unitv[(size_t)e * 3 + 0];
        float uy = unitv[(size_t)e * 3 + 1];
        float uz = unitv[(size_t)e * 3 + 2];
        float nM = fmaxf(Mx, logit);
        float scale = __expf(Mx - nM);
        float w = __expf(logit - nM);
        S = S * scale + w;
        float wv = w * vve;
        am = am * scale + wv;
        a0 = a0 * scale + wv * ux;
        a1 = a1 * scale + wv * uy;
        a2 = a2 * scale + wv * uz;
        Mx = nM;
    }
    float inv = 1.0f / (S + 1e-12f);
    msg[(size_t)i * 128 + m] = am * inv;
    U[((size_t)i * 3 + 0) * 128 + m] = a0 * inv;
    U[((size_t)i * 3 + 1) * 128 + m] = a1 * inv;
    U[((size_t)i * 3 + 2) * 128 + m] = a2 * inv;
}

// ---------------------------------------------------------------------------
// vnorm[i,d] = sqrt(sum_xyz vfeat[i,x,d]^2 + 1e-8)
// ---------------------------------------------------------------------------
__global__ __launch_bounds__(256) void vnorm_kernel(
    const float* __restrict__ vfeat, float* __restrict__ vn)
{
    int i = blockIdx.x, d = threadIdx.x;
    float v0 = vfeat[((size_t)i * 3 + 0) * 256 + d];
    float v1 = vfeat[((size_t)i * 3 + 1) * 256 + d];
    float v2 = vfeat[((size_t)i * 3 + 2) * 256 + d];
    vn[(size_t)i * 256 + d] = sqrtf(v0 * v0 + v1 * v1 + v2 * v2 + 1e-8f);
}

// ---------------------------------------------------------------------------
// h = layernorm(h + add) * gamma
// ---------------------------------------------------------------------------
__global__ __launch_bounds__(256) void ln_kernel(
    float* __restrict__ h, const float* __restrict__ add, const float* __restrict__ gamma_l)
{
    __shared__ float lds[4];
    int i = blockIdx.x, d = threadIdx.x;
    size_t idx = (size_t)i * 256 + d;
    float x = h[idx] + add[idx];
    float s = x;
    #pragma unroll
    for (int off = 32; off; off >>= 1) s += __shfl_xor(s, off);
    if ((d & 63) == 0) lds[d >> 6] = s;
    __syncthreads();
    float mu = (lds[0] + lds[1] + lds[2] + lds[3]) * (1.0f / 256.0f);
    __syncthreads();
    float xc = x - mu;
    float v = xc * xc;
    #pragma unroll
    for (int off = 32; off; off >>= 1) v += __shfl_xor(v, off);
    if ((d & 63) == 0) lds[d >> 6] = v;
    __syncthreads();
    float var = (lds[0] + lds[1] + lds[2] + lds[3]) * (1.0f / 256.0f);
    h[idx] = xc * rsqrtf(var + 1e-5f) * gamma_l[d];
}

// ---------------------------------------------------------------------------
// Graph pooling: softmax(h @ w_att) weighted sum per graph (batch sorted)
// ---------------------------------------------------------------------------
__global__ __launch_bounds__(256) void pool_kernel(
    const float* __restrict__ h, const float* __restrict__ w_att,
    const int* __restrict__ gptr, float* __restrict__ pooled)
{
    __shared__ float lds[4];
    int g = blockIdx.x, d = threadIdx.x;
    float wa = w_att[d];
    int n0 = gptr[g], n1 = gptr[g + 1];
    float M = -1e30f, S = 0.f, acc = 0.f;
    for (int i = n0; i < n1; ++i) {
        float hv = h[(size_t)i * 256 + d];
        float p = hv * wa;
        #pragma unroll
        for (int off = 32; off; off >>= 1) p += __shfl_xor(p, off);
        if ((d & 63) == 0) lds[d >> 6] = p;
        __syncthreads();
        float logit = lds[0] + lds[1] + lds[2] + lds[3];
        __syncthreads();
        float nM = fmaxf(M, logit);
        float sc = __expf(M - nM);
        float w  = __expf(logit - nM);
        S = S * sc + w;
        acc = acc * sc + w * hv;
        M = nM;
    }
    pooled[(size_t)g * 256 + d] = acc / (S + 1e-12f);
}

// ---------------------------------------------------------------------------
// out[g,c] = pooled[g,:] @ W_out[:,c] + b_out[c]
// ---------------------------------------------------------------------------
__global__ __launch_bounds__(512) void out_kernel(
    const float* __restrict__ pooled, const float* __restrict__ W_out,
    const float* __restrict__ b_out, float* __restrict__ outp)
{
    __shared__ float ps[256];
    int g = blockIdx.x, c = threadIdx.x;
    if (c < 256) ps[c] = pooled[(size_t)g * 256 + c];
    __syncthreads();
    float acc = b_out[c];
    for (int k = 0; k < 256; ++k)
        acc += ps[k] * W_out[k * 512 + c];
    outp[(size_t)g * 512 + c] = acc;
}

// ---------------------------------------------------------------------------
extern "C" void kernel_launch(void* const* d_in, const int* in_sizes, int n_in,
                              void* d_out, int out_size, void* d_ws, size_t ws_size,
                              hipStream_t stream)
{
    const float* pos   = (const float*)d_in[0];
    const int*   z     = (const int*)d_in[1];
    const int*   batch = (const int*)d_in[2];
    const int*   ei    = (const int*)d_in[3];
    const float* emb   = (const float*)d_in[4];
    const float* W_in  = (const float*)d_in[5];
    const float* b_in  = (const float*)d_in[6];
    const float* Wq    = (const float*)d_in[7];
    const float* Wk    = (const float*)d_in[8];
    const float* Wv    = (const float*)d_in[9];
    const float* W_rbf = (const float*)d_in[10];
    const float* W_msg = (const float*)d_in[11];
    const float* W_vg  = (const float*)d_in[12];
    const float* W_vs  = (const float*)d_in[13];
    const float* W_nd  = (const float*)d_in[14];
    const float* b_nd  = (const float*)d_in[15];
    const float* gam   = (const float*)d_in[16];
    const float* watt  = (const float*)d_in[17];
    const float* W_out = (const float*)d_in[18];
    const float* b_out = (const float*)d_in[19];

    const int N = in_sizes[0] / 3;      // 20000
    const int E = in_sizes[3] / 2;      // 320000
    const int G = out_size / 512;       // 500

    char* ws = (char*)d_ws;
    size_t o = 0;
    auto alloc = [&](size_t bytes) -> char* {
        o = (o + 255) & ~(size_t)255;
        char* r = ws + o;
        o += bytes;
        return r;
    };
    float* f_dist = (float*)alloc((size_t)E * 4);
    float* f_unit = (float*)alloc((size_t)E * 3 * 4);
    float* f_h    = (float*)alloc((size_t)N * 256 * 4);
    float* f_vf   = (float*)alloc((size_t)N * 3 * 256 * 4);
    float* f_qkv  = (float*)alloc((size_t)N * 384 * 4);
    float* f_msg  = (float*)alloc((size_t)N * 128 * 4);
    float* f_U    = (float*)alloc((size_t)N * 3 * 128 * 4);
    float* f_pool = (float*)alloc((size_t)G * 256 * 4);
    // split weights: per-layer {qkvT 384x256, vgT 256x128, msgT 256x128,
    //                           ndT 256x256, vsT 256x256}
    const size_t LS = 384 * 256 + 2 * (256 * 128) + 2 * (256 * 256);   // 294912
    const size_t OFF_QKV = 0, OFF_VG = 384 * 256, OFF_MSG = OFF_VG + 256 * 128,
                 OFF_ND = OFF_MSG + 256 * 128, OFF_VS = OFF_ND + 256 * 256;
    u16* whi = (u16*)alloc(LS * 4 * sizeof(u16));
    u16* wlo = (u16*)alloc(LS * 4 * sizeof(u16));
    int* i_deg  = (int*)alloc((size_t)N * 4);
    int* i_rowp = (int*)alloc((size_t)(N + 1) * 4);
    int* i_cur  = (int*)alloc((size_t)(N + 1) * 4);
    int* i_perm = (int*)alloc((size_t)E * 4);
    int* i_gcnt = (int*)alloc((size_t)G * 4);
    int* i_gptr = (int*)alloc((size_t)(G + 1) * 4);

    // aliases over dead regions:
    float* f_b1 = f_U;      // [N,256]: written after U consumed by vgate GEMM
    float* f_b2 = f_qkv;    // [N,256]: written after qkv consumed by edge_attn

    // ---- weight pre-pass descriptor ----
    TDesc td;
    int idx = 0;
    for (int l = 0; l < 4; ++l) {
        u16* bh = whi + (size_t)l * LS;
        u16* bl = wlo + (size_t)l * LS;
        td.e[idx++] = { Wq   + (size_t)l * 256 * 128, bh + OFF_QKV,             bl + OFF_QKV,             256, 128 };
        td.e[idx++] = { Wk   + (size_t)l * 256 * 128, bh + OFF_QKV + 128 * 256, bl + OFF_QKV + 128 * 256, 256, 128 };
        td.e[idx++] = { Wv   + (size_t)l * 256 * 128, bh + OFF_QKV + 256 * 256, bl + OFF_QKV + 256 * 256, 256, 128 };
        td.e[idx++] = { W_vg + (size_t)l * 128 * 256, bh + OFF_VG,  bl + OFF_VG,  128, 256 };
        td.e[idx++] = { W_msg+ (size_t)l * 128 * 256, bh + OFF_MSG, bl + OFF_MSG, 128, 256 };
        td.e[idx++] = { W_nd + (size_t)l * 256 * 256, bh + OFF_ND,  bl + OFF_ND,  256, 256 };
        td.e[idx++] = { W_vs + (size_t)l * 256 * 256, bh + OFF_VS,  bl + OFF_VS,  256, 256 };
    }

    // ---- setup ----
    zero_i32<<<(N + 255) / 256, 256, 0, stream>>>(i_deg, N);
    zero_i32<<<(G + 255) / 256, 256, 0, stream>>>(i_gcnt, G);
    zero_f32<<<2048, 256, 0, stream>>>(f_vf, (size_t)N * 3 * 256);
    transpose_split<<<dim3(64, 28), 256, 0, stream>>>(td);

    hist_edges<<<(E + 255) / 256, 256, 0, stream>>>(ei, i_deg, E);
    scan_kernel<<<1, 1024, 0, stream>>>(i_deg, N, i_rowp, i_cur);
    scatter_kernel<<<(E + 255) / 256, 256, 0, stream>>>(ei, i_cur, i_perm, E);
    hist_nodes<<<(N + 255) / 256, 256, 0, stream>>>(batch, i_gcnt, N);
    scan_kernel<<<1, 1024, 0, stream>>>(i_gcnt, G, i_gptr, (int*)nullptr);
    geom_kernel<<<(E + 255) / 256, 256, 0, stream>>>(pos, ei, f_dist, f_unit, E);
    init_h_kernel<<<N, 256, 0, stream>>>(z, pos, emb, W_in, b_in, f_h);

    const int MB  = (N + 127) / 128;          // 157
    const int MB3 = (3 * N + 127) / 128;      // 469

    // ---- layers ----
    for (int l = 0; l < 4; ++l) {
        u16* bh = whi + (size_t)l * LS;
        u16* bl = wlo + (size_t)l * LS;
        const float* Wrbf_l = W_rbf + (size_t)l * 32 * 128;
        const float* bnd_l  = b_nd  + (size_t)l * 256;
        const float* gam_l  = gam   + (size_t)l * 256;

        // qkv = h @ [Wq|Wk|Wv]   [N,256]@[256,384]
        mfma_gemm<false,false,false><<<dim3(3, MB), 256, 0, stream>>>(
            f_h, bh + OFF_QKV, bl + OFF_QKV, nullptr, f_qkv, N, 256, 384);

        edge_attn_kernel<<<N, 128, 0, stream>>>(i_rowp, i_perm, ei, f_qkv,
                                                f_dist, f_unit, Wrbf_l, f_msg, f_U);

        // vfeat += U @ W_vgate   [3N,128]@[128,256]
        mfma_gemm<true,false,false><<<dim3(2, MB3), 256, 0, stream>>>(
            f_U, bh + OFF_VG, bl + OFF_VG, nullptr, f_vf, 3 * N, 128, 256);

        // b1 = gelu(msg @ W_msg)  (overwrites dead U)
        mfma_gemm<false,false,true><<<dim3(2, MB), 256, 0, stream>>>(
            f_msg, bh + OFF_MSG, bl + OFF_MSG, nullptr, f_b1, N, 128, 256);
        // b2 = gelu(b1 @ W_node + b_node)  (overwrites dead qkv)
        mfma_gemm<false,true,true><<<dim3(2, MB), 256, 0, stream>>>(
            f_b1, bh + OFF_ND, bl + OFF_ND, bnd_l, f_b2, N, 256, 256);
        // b1 = vnorm(vfeat)
        vnorm_kernel<<<N, 256, 0, stream>>>(f_vf, f_b1);
        // b2 += vnorm @ W_vs
        mfma_gemm<true,false,false><<<dim3(2, MB), 256, 0, stream>>>(
            f_b1, bh + OFF_VS, bl + OFF_VS, nullptr, f_b2, N, 256, 256);

        ln_kernel<<<N, 256, 0, stream>>>(f_h, f_b2, gam_l);
    }

    // ---- readout ----
    pool_kernel<<<G, 256, 0, stream>>>(f_h, watt, i_gptr, f_pool);
    out_kernel<<<G, 512, 0, stream>>>(f_pool, W_out, b_out, (float*)d_out);
}